// Round 6
// baseline (617.094 us; speedup 1.0000x reference)
//
#include <hip/hip_runtime.h>

#define NR 4096
#define BN_EPS 1e-5f

// ---- d_out offsets (floats), concatenated in reference return order ----
#define OFF_LATENT 0
#define OFF_D1     131072
#define OFF_D2     172032
#define OFF_Q      212992
#define OFF_P      16990208
#define OFF_NUM    33767424
#define OFF_NORM   50544640

// ---- workspace offsets (floats) — small accumulators only (~85 KB) ----
#define WS_SUM0   0
#define WS_SQ0    256
#define WS_SUM1   512
#define WS_SQ1    576
#define WS_ROWSUM 640
#define WS_ZERO_F 4736          // floats to zero (atomic accumulators)
#define WS_DIAG   4736
#define WS_SUMY   8832

// ---- scratch inside d_out's latent_q region (16.77M floats, written last) ----
// H0 1,048,576 | H1 262,144 | P0 10x1,048,576 | P1 4x262,144  (12.85M total)
#define SCR_H0 0
#define SCR_H1 1048576
#define SCR_P0 1310720
#define SCR_P1 11796480

// ============ zero the atomic accumulators (graph-capture-safe) ============
__global__ void zero_ws(float* __restrict__ ws) {
    int i = blockIdx.x * blockDim.x + threadIdx.x;
    if (i < WS_ZERO_F) ws[i] = 0.0f;
}

// ============ split-K GEMM, NON-ATOMIC partials: P[z] = A_chunk @ B_chunk^T ====
// 128x64 tile, 8x4 micro-tile, BK=16, 256 threads, register-staged prefetch.
// kc = kcB + (z<extra ? 16:0); kb = z*kcB + min(z,extra)*16  (uneven K split)
__global__ __launch_bounds__(256) void gemm_partial_128x64(
    const float* __restrict__ A, const float* __restrict__ B,
    float* __restrict__ P, int lda, int ldb, int ldn,
    int kcB, int extra, int pstride)
{
    __shared__ float As[16][128];   // transposed: As[k][row]
    __shared__ float Bs[16][64];
    const int t  = threadIdx.x;
    const int tx = t & 15;          // col group (4 cols)
    const int ty = t >> 4;          // row group (8 rows)
    const int i0 = blockIdx.x * 128;
    const int n0 = blockIdx.y * 64;
    const int z  = blockIdx.z;
    const int kc = kcB + (z < extra ? 16 : 0);
    const int kb = z * kcB + (z < extra ? z : extra) * 16;

    const int ra  = t >> 1;         // 0..127 (A row)
    const int ka  = (t & 1) * 8;    // 0 or 8
    const int rb  = t >> 2;         // 0..63  (B row)
    const int kbq = (t & 3) * 4;    // 0,4,8,12

    const float* pA = &A[(size_t)(i0 + ra) * lda + kb + ka];
    const float* pB = &B[(size_t)(n0 + rb) * ldb + kb + kbq];

    float acc[8][4] = {};

    float4 a0 = *(const float4*)(pA);
    float4 a1 = *(const float4*)(pA + 4);
    float4 b0 = *(const float4*)(pB);

    for (int kt = 0; kt < kc; kt += 16) {
        __syncthreads();
        As[ka+0][ra] = a0.x; As[ka+1][ra] = a0.y; As[ka+2][ra] = a0.z; As[ka+3][ra] = a0.w;
        As[ka+4][ra] = a1.x; As[ka+5][ra] = a1.y; As[ka+6][ra] = a1.z; As[ka+7][ra] = a1.w;
        Bs[kbq+0][rb] = b0.x; Bs[kbq+1][rb] = b0.y; Bs[kbq+2][rb] = b0.z; Bs[kbq+3][rb] = b0.w;
        __syncthreads();
        if (kt + 16 < kc) {         // next-tile loads in flight during compute
            a0 = *(const float4*)(pA + kt + 16);
            a1 = *(const float4*)(pA + kt + 20);
            b0 = *(const float4*)(pB + kt + 16);
        }
        #pragma unroll
        for (int k = 0; k < 16; ++k) {
            float4 av0 = *(const float4*)&As[k][ty*8];
            float4 av1 = *(const float4*)&As[k][ty*8+4];
            float4 bv  = *(const float4*)&Bs[k][tx*4];
            float am[8] = {av0.x,av0.y,av0.z,av0.w,av1.x,av1.y,av1.z,av1.w};
            float bb[4] = {bv.x,bv.y,bv.z,bv.w};
            #pragma unroll
            for (int m = 0; m < 8; ++m)
                #pragma unroll
                for (int n = 0; n < 4; ++n)
                    acc[m][n] = fmaf(am[m], bb[n], acc[m][n]);
        }
    }
    float* dst = P + (size_t)z * pstride;
    #pragma unroll
    for (int m = 0; m < 8; ++m)
        *(float4*)&dst[(size_t)(i0 + ty*8 + m) * ldn + n0 + tx*4] =
            make_float4(acc[m][0], acc[m][1], acc[m][2], acc[m][3]);
}

// ============ H = bias + sum_z P[z]  (deterministic K-reduction) ============
__global__ void reduce_bias(const float* __restrict__ P, const float* __restrict__ bias,
                            float* __restrict__ H, int nz, int pstride4, int cols4)
{
    int i4 = blockIdx.x * blockDim.x + threadIdx.x;
    float4 a = ((const float4*)bias)[i4 & (cols4 - 1)];
    for (int z = 0; z < nz; ++z) {
        float4 v = ((const float4*)P)[(size_t)z * pstride4 + i4];
        a.x += v.x; a.y += v.y; a.z += v.z; a.w += v.w;
    }
    ((float4*)H)[i4] = a;
}

// ============ BatchNorm column stats: sum / sumsq via atomics ============
__global__ void bn_stats(const float* __restrict__ H, float* __restrict__ sum,
                         float* __restrict__ sumsq, int cols)
{
    const int t = threadIdx.x;
    const int col = t & (cols - 1);
    const int sub = t / cols;
    const int rstep = 256 / cols;
    const int rbase = blockIdx.x * 16;
    float s = 0.f, sq = 0.f;
    for (int r = sub; r < 16; r += rstep) {
        float v = H[(size_t)(rbase + r) * cols + col];
        s += v; sq += v * v;
    }
    atomicAdd(&sum[col], s);
    atomicAdd(&sumsq[col], sq);
}

// ============ BN apply + ReLU (in place, float4) ============
__global__ void bn_relu(float* __restrict__ H, const float* __restrict__ sum,
                        const float* __restrict__ sumsq, const float* __restrict__ g,
                        const float* __restrict__ beta, int cols)
{
    int i4 = blockIdx.x * blockDim.x + threadIdx.x;
    float4 v = ((const float4*)H)[i4];
    int c0 = (i4 * 4) & (cols - 1);
    float o[4] = {v.x, v.y, v.z, v.w};
    #pragma unroll
    for (int e = 0; e < 4; ++e) {
        int c = c0 + e;
        float mu  = sum[c]   * (1.0f / 4096.0f);
        float var = sumsq[c] * (1.0f / 4096.0f) - mu * mu;
        float xn = (o[e] - mu) / sqrtf(var + BN_EPS);
        o[e] = fmaxf(g[c] * xn + beta[c], 0.0f);
    }
    ((float4*)H)[i4] = make_float4(o[0], o[1], o[2], o[3]);
}

// ============ latent = H1 @ W2^T + b2, fused normalize + cluster dists ============
__global__ __launch_bounds__(256) void latent_kernel(
    const float* __restrict__ H1, const float* __restrict__ W2,
    const float* __restrict__ b2, const float* __restrict__ centers,
    float* __restrict__ out_latent, float* __restrict__ out_norm,
    float* __restrict__ out_d1, float* __restrict__ out_d2,
    float* __restrict__ sumy)
{
    __shared__ float W2T[64][32];
    __shared__ float cent[320];
    __shared__ float b2s[32];
    __shared__ float Hs[8][64];
    const int t = threadIdx.x;
    {   // stage W2 transposed: W2 is [32][64] row-major
        int c = t >> 3, dd = (t & 7) * 8;
        #pragma unroll
        for (int q = 0; q < 8; ++q) W2T[dd + q][c] = W2[c * 64 + dd + q];
    }
    for (int c = t; c < 320; c += 256) cent[c] = centers[c];
    if (t < 32) b2s[t] = b2[t];
    const int base = blockIdx.x * 8;
    if (t < 128) {
        int rr = t >> 4, off = (t & 15) * 4;
        *(float4*)&Hs[rr][off] = *(const float4*)&H1[(size_t)(base + rr) * 64 + off];
    }
    __syncthreads();

    const int g = t >> 5, lane = t & 31;
    const int row = base + g;
    float acc = b2s[lane];
    #pragma unroll
    for (int d = 0; d < 64; ++d) acc = fmaf(Hs[g][d], W2T[d][lane], acc);
    out_latent[(size_t)row * 32 + lane] = acc;

    float ss = acc * acc;
    #pragma unroll
    for (int off = 16; off; off >>= 1) ss += __shfl_xor(ss, off);
    float denom = fmaxf(sqrtf(ss), 1e-12f);
    out_norm[(size_t)row * 32 + lane] = acc / denom;
    if (lane == 0) sumy[row] = ss;

    float qsum = 0.f, myx1 = 0.f, myqc = 0.f;
    #pragma unroll
    for (int k = 0; k < 10; ++k) {
        float dv = acc - cent[k * 32 + lane];
        float sq = dv * dv;
        #pragma unroll
        for (int off = 16; off; off >>= 1) sq += __shfl_xor(sq, off);
        float x1 = 1.0f + sq;
        float qc = 1.0f / x1;
        qsum += qc;
        if (lane == k) { myx1 = x1; myqc = qc; }
    }
    if (lane < 10) {
        out_d2[row * 10 + lane] = myx1;
        out_d1[row * 10 + lane] = myqc / qsum;
    }
}

// ============ num kernel v2: 128x64 tile, transposed LDS, COALESCED float4 stores ==
// num[i][j] = 1/(1 + sy_i + sy_j - 2*dot(l_i,l_j)); per-row partial sums + diag.
// (v1 did 64 scalar stores/thread at 64B stride — non-coalesced.)
__global__ __launch_bounds__(256) void num_kernel(
    const float* __restrict__ latent, const float* __restrict__ sumy,
    float* __restrict__ num_out, float* __restrict__ rowsum, float* __restrict__ diagv)
{
    __shared__ float LiT[32][128];  // d-major
    __shared__ float LjT[32][64];
    __shared__ float scr[128];
    const int t  = threadIdx.x;
    const int i0 = blockIdx.x * 128;
    const int j0 = blockIdx.y * 64;
    {   // stage A transposed: 2 threads/row, 16 floats each
        int r = t >> 1, h = (t & 1) * 16;
        const float* src = &latent[(size_t)(i0 + r) * 32 + h];
        float4 v0 = *(const float4*)(src),     v1 = *(const float4*)(src + 4);
        float4 v2 = *(const float4*)(src + 8), v3 = *(const float4*)(src + 12);
        LiT[h+ 0][r]=v0.x; LiT[h+ 1][r]=v0.y; LiT[h+ 2][r]=v0.z; LiT[h+ 3][r]=v0.w;
        LiT[h+ 4][r]=v1.x; LiT[h+ 5][r]=v1.y; LiT[h+ 6][r]=v1.z; LiT[h+ 7][r]=v1.w;
        LiT[h+ 8][r]=v2.x; LiT[h+ 9][r]=v2.y; LiT[h+10][r]=v2.z; LiT[h+11][r]=v2.w;
        LiT[h+12][r]=v3.x; LiT[h+13][r]=v3.y; LiT[h+14][r]=v3.z; LiT[h+15][r]=v3.w;
    }
    {   // stage B transposed: 4 threads/row, 8 floats each
        int r = t >> 2, h = (t & 3) * 8;
        const float* src = &latent[(size_t)(j0 + r) * 32 + h];
        float4 v0 = *(const float4*)(src), v1 = *(const float4*)(src + 4);
        LjT[h+0][r]=v0.x; LjT[h+1][r]=v0.y; LjT[h+2][r]=v0.z; LjT[h+3][r]=v0.w;
        LjT[h+4][r]=v1.x; LjT[h+5][r]=v1.y; LjT[h+6][r]=v1.z; LjT[h+7][r]=v1.w;
    }
    if (t < 128) scr[t] = 0.f;
    __syncthreads();

    const int tx = t & 15, ty = t >> 4;   // rows: ty*8+m, cols: tx*4+q
    float acc[8][4] = {};
    #pragma unroll
    for (int d = 0; d < 32; ++d) {
        float4 bv = *(const float4*)&LjT[d][tx*4];
        float bb[4] = {bv.x, bv.y, bv.z, bv.w};
        #pragma unroll
        for (int m = 0; m < 8; ++m) {
            float a = LiT[d][ty*8 + m];
            #pragma unroll
            for (int q = 0; q < 4; ++q)
                acc[m][q] = fmaf(a, bb[q], acc[m][q]);
        }
    }
    float4 sj4 = *(const float4*)&sumy[j0 + tx*4];
    float syj[4] = {sj4.x, sj4.y, sj4.z, sj4.w};
    float racc[8];
    #pragma unroll
    for (int m = 0; m < 8; ++m) {
        const int i = i0 + ty*8 + m;
        const float syi = sumy[i];
        float vq[4];
        racc[m] = 0.f;
        #pragma unroll
        for (int q = 0; q < 4; ++q) {
            const int j = j0 + tx*4 + q;
            float sq = syi + syj[q] - 2.0f * acc[m][q];
            float v = 1.0f / (1.0f + sq);
            vq[q] = v;
            racc[m] += v;
            if (i == j) diagv[i] = v;
        }
        *(float4*)&num_out[(size_t)i * NR + j0 + tx*4] =
            make_float4(vq[0], vq[1], vq[2], vq[3]);
    }
    __syncthreads();
    #pragma unroll
    for (int m = 0; m < 8; ++m) atomicAdd(&scr[ty*8 + m], racc[m]);
    __syncthreads();
    if (t < 128) atomicAdd(&rowsum[i0 + t], scr[t]);
}

// ============ fused p+q kernel: one block per row, p kept in registers ============
__global__ __launch_bounds__(256) void pq_kernel(
    const float* __restrict__ num, const float* __restrict__ rowsum,
    const float* __restrict__ diagv, float* __restrict__ p_out,
    float* __restrict__ q_out)
{
    const int i = blockIdx.x;
    const int t = threadIdx.x;
    const float dg = diagv[i];
    const float inv_S1 = 1.0f / (rowsum[i] - dg);
    const float* nrow = &num[(size_t)i * NR];
    float* prow = &p_out[(size_t)i * NR];
    float* qrow = &q_out[(size_t)i * NR];

    float pr[16];
    float s = 0.f, s2 = 0.f;
    #pragma unroll
    for (int it = 0; it < 4; ++it) {
        int j4 = it * 256 + t;
        float4 v = ((const float4*)nrow)[j4];
        float vv[4] = {v.x, v.y, v.z, v.w};
        #pragma unroll
        for (int e = 0; e < 4; ++e) {
            int j = j4 * 4 + e;
            float p = (j == i) ? 0.0f : vv[e] * inv_S1;
            pr[it * 4 + e] = p;
            s += p; s2 += p * p;
        }
        ((float4*)prow)[j4] = make_float4(
            (j4*4+0 == i) ? dg : pr[it*4+0], (j4*4+1 == i) ? dg : pr[it*4+1],
            (j4*4+2 == i) ? dg : pr[it*4+2], (j4*4+3 == i) ? dg : pr[it*4+3]);
    }
    #pragma unroll
    for (int off = 32; off; off >>= 1) {
        s  += __shfl_xor(s, off);
        s2 += __shfl_xor(s2, off);
    }
    __shared__ float rA[4], rB[4];
    const int wid = t >> 6;
    if ((t & 63) == 0) { rA[wid] = s; rB[wid] = s2; }
    __syncthreads();
    const float sp  = rA[0] + rA[1] + rA[2] + rA[3];
    const float sp2 = rB[0] + rB[1] + rB[2] + rB[3];
    const float inv_sp   = 1.0f / sp;
    const float inv_sumq = sp / sp2;     // 1 / (sp2/sp)
    #pragma unroll
    for (int it = 0; it < 4; ++it) {
        int j4 = it * 256 + t;
        float qv[4];
        #pragma unroll
        for (int e = 0; e < 4; ++e) {
            int j = j4 * 4 + e;
            float p = pr[it * 4 + e];
            qv[e] = (j == i) ? dg : (p * p * inv_sp) * inv_sumq;
        }
        ((float4*)qrow)[j4] = make_float4(qv[0], qv[1], qv[2], qv[3]);
    }
}

// ===================== launch =====================
extern "C" void kernel_launch(void* const* d_in, const int* in_sizes, int n_in,
                              void* d_out, int out_size, void* d_ws, size_t ws_size,
                              hipStream_t stream) {
    const float* x       = (const float*)d_in[0];
    const float* W0      = (const float*)d_in[1];
    const float* b0      = (const float*)d_in[2];
    const float* g0      = (const float*)d_in[3];
    const float* beta0   = (const float*)d_in[4];
    const float* W1      = (const float*)d_in[5];
    const float* b1      = (const float*)d_in[6];
    const float* g1      = (const float*)d_in[7];
    const float* beta1   = (const float*)d_in[8];
    const float* W2      = (const float*)d_in[9];
    const float* b2      = (const float*)d_in[10];
    const float* centers = (const float*)d_in[11];
    float* out = (float*)d_out;
    float* ws  = (float*)d_ws;

    // Scratch lives in d_out's latent_q region (dead until pq_kernel).
    float* scr = out + OFF_Q;
    float* H0 = scr + SCR_H0;
    float* H1 = scr + SCR_H1;
    float* P0 = scr + SCR_P0;
    float* P1 = scr + SCR_P1;

    zero_ws<<<19, 256, 0, stream>>>(ws);     // sum0/sq0/sum1/sq1/rowsum

    // ---- layer 0: H0 = x @ W0^T + b0, BN, ReLU (split-K z=10, non-atomic) ----
    gemm_partial_128x64<<<dim3(32, 4, 10), 256, 0, stream>>>(
        x, W0, P0, 2000, 2000, 256, 192, 5, 1048576);
    reduce_bias<<<1024, 256, 0, stream>>>(P0, b0, H0, 10, 262144, 64);
    bn_stats<<<256, 256, 0, stream>>>(H0, ws + WS_SUM0, ws + WS_SQ0, 256);
    bn_relu<<<1024, 256, 0, stream>>>(H0, ws + WS_SUM0, ws + WS_SQ0, g0, beta0, 256);

    // ---- layer 1: H1 = H0 @ W1^T + b1, BN, ReLU (split-K z=4, non-atomic) ----
    gemm_partial_128x64<<<dim3(32, 1, 4), 256, 0, stream>>>(
        H0, W1, P1, 256, 256, 64, 64, 0, 262144);
    reduce_bias<<<256, 256, 0, stream>>>(P1, b1, H1, 4, 65536, 16);
    bn_stats<<<256, 256, 0, stream>>>(H1, ws + WS_SUM1, ws + WS_SQ1, 64);
    bn_relu<<<256, 256, 0, stream>>>(H1, ws + WS_SUM1, ws + WS_SQ1, g1, beta1, 64);

    latent_kernel<<<512, 256, 0, stream>>>(H1, W2, b2, centers,
        out + OFF_LATENT, out + OFF_NORM, out + OFF_D1, out + OFF_D2, ws + WS_SUMY);

    num_kernel<<<dim3(32, 64), 256, 0, stream>>>(out + OFF_LATENT, ws + WS_SUMY,
        out + OFF_NUM, ws + WS_ROWSUM, ws + WS_DIAG);

    pq_kernel<<<4096, 256, 0, stream>>>(out + OFF_NUM, ws + WS_ROWSUM, ws + WS_DIAG,
        out + OFF_P, out + OFF_Q);
}

// Round 8
// 549.421 us; speedup vs baseline: 1.1232x; 1.1232x over previous
//
#include <hip/hip_runtime.h>

#define NR 4096
#define BN_EPS 1e-5f

// ---- d_out offsets (floats), concatenated in reference return order ----
#define OFF_LATENT 0
#define OFF_D1     131072
#define OFF_D2     172032
#define OFF_Q      212992
#define OFF_P      16990208
#define OFF_NUM    33767424
#define OFF_NORM   50544640

// ---- workspace offsets (floats) — small accumulators only (~85 KB) ----
#define WS_SUM0   0
#define WS_SQ0    256
#define WS_SUM1   512
#define WS_SQ1    576
#define WS_ROWSUM 640
#define WS_ZERO_F 4736          // floats to zero (atomic accumulators)
#define WS_DIAG   4736
#define WS_SUMY   8832

// ---- scratch inside d_out's latent_q region (16.77M floats, written last) ----
#define SCR_H0 0
#define SCR_H1 1048576
#define SCR_P0 1310720
#define SCR_P1 11796480

// ============ zero the atomic accumulators (graph-capture-safe) ============
__global__ void zero_ws(float* __restrict__ ws) {
    int i = blockIdx.x * blockDim.x + threadIdx.x;
    if (i < WS_ZERO_F) ws[i] = 0.0f;
}

// ============ split-K GEMM, NON-ATOMIC partials: P[z] = A_chunk @ B_chunk^T ====
// 128x64 tile, 8x4 micro-tile, BK=16, 256 threads, register-staged prefetch.
__global__ __launch_bounds__(256) void gemm_partial_128x64(
    const float* __restrict__ A, const float* __restrict__ B,
    float* __restrict__ P, int lda, int ldb, int ldn,
    int kcB, int extra, int pstride)
{
    __shared__ float As[16][128];   // transposed: As[k][row]
    __shared__ float Bs[16][64];
    const int t  = threadIdx.x;
    const int tx = t & 15;          // col group (4 cols)
    const int ty = t >> 4;          // row group (8 rows)
    const int i0 = blockIdx.x * 128;
    const int n0 = blockIdx.y * 64;
    const int z  = blockIdx.z;
    const int kc = kcB + (z < extra ? 16 : 0);
    const int kb = z * kcB + (z < extra ? z : extra) * 16;

    const int ra  = t >> 1;         // 0..127 (A row)
    const int ka  = (t & 1) * 8;    // 0 or 8
    const int rb  = t >> 2;         // 0..63  (B row)
    const int kbq = (t & 3) * 4;    // 0,4,8,12

    const float* pA = &A[(size_t)(i0 + ra) * lda + kb + ka];
    const float* pB = &B[(size_t)(n0 + rb) * ldb + kb + kbq];

    float acc[8][4] = {};

    float4 a0 = *(const float4*)(pA);
    float4 a1 = *(const float4*)(pA + 4);
    float4 b0 = *(const float4*)(pB);

    for (int kt = 0; kt < kc; kt += 16) {
        __syncthreads();
        As[ka+0][ra] = a0.x; As[ka+1][ra] = a0.y; As[ka+2][ra] = a0.z; As[ka+3][ra] = a0.w;
        As[ka+4][ra] = a1.x; As[ka+5][ra] = a1.y; As[ka+6][ra] = a1.z; As[ka+7][ra] = a1.w;
        Bs[kbq+0][rb] = b0.x; Bs[kbq+1][rb] = b0.y; Bs[kbq+2][rb] = b0.z; Bs[kbq+3][rb] = b0.w;
        __syncthreads();
        if (kt + 16 < kc) {         // next-tile loads in flight during compute
            a0 = *(const float4*)(pA + kt + 16);
            a1 = *(const float4*)(pA + kt + 20);
            b0 = *(const float4*)(pB + kt + 16);
        }
        #pragma unroll
        for (int k = 0; k < 16; ++k) {
            float4 av0 = *(const float4*)&As[k][ty*8];
            float4 av1 = *(const float4*)&As[k][ty*8+4];
            float4 bv  = *(const float4*)&Bs[k][tx*4];
            float am[8] = {av0.x,av0.y,av0.z,av0.w,av1.x,av1.y,av1.z,av1.w};
            float bb[4] = {bv.x,bv.y,bv.z,bv.w};
            #pragma unroll
            for (int m = 0; m < 8; ++m)
                #pragma unroll
                for (int n = 0; n < 4; ++n)
                    acc[m][n] = fmaf(am[m], bb[n], acc[m][n]);
        }
    }
    float* dst = P + (size_t)z * pstride;
    #pragma unroll
    for (int m = 0; m < 8; ++m)
        *(float4*)&dst[(size_t)(i0 + ty*8 + m) * ldn + n0 + tx*4] =
            make_float4(acc[m][0], acc[m][1], acc[m][2], acc[m][3]);
}

// ============ H = bias + sum_z P[z]  (deterministic K-reduction) ============
__global__ void reduce_bias(const float* __restrict__ P, const float* __restrict__ bias,
                            float* __restrict__ H, int nz, int pstride4, int cols4)
{
    int i4 = blockIdx.x * blockDim.x + threadIdx.x;
    float4 a = ((const float4*)bias)[i4 & (cols4 - 1)];
    for (int z = 0; z < nz; ++z) {
        float4 v = ((const float4*)P)[(size_t)z * pstride4 + i4];
        a.x += v.x; a.y += v.y; a.z += v.z; a.w += v.w;
    }
    ((float4*)H)[i4] = a;
}

// ============ BatchNorm column stats: sum / sumsq via atomics ============
__global__ void bn_stats(const float* __restrict__ H, float* __restrict__ sum,
                         float* __restrict__ sumsq, int cols)
{
    const int t = threadIdx.x;
    const int col = t & (cols - 1);
    const int sub = t / cols;
    const int rstep = 256 / cols;
    const int rbase = blockIdx.x * 16;
    float s = 0.f, sq = 0.f;
    for (int r = sub; r < 16; r += rstep) {
        float v = H[(size_t)(rbase + r) * cols + col];
        s += v; sq += v * v;
    }
    atomicAdd(&sum[col], s);
    atomicAdd(&sumsq[col], sq);
}

// ============ BN apply + ReLU (in place, float4) ============
__global__ void bn_relu(float* __restrict__ H, const float* __restrict__ sum,
                        const float* __restrict__ sumsq, const float* __restrict__ g,
                        const float* __restrict__ beta, int cols)
{
    int i4 = blockIdx.x * blockDim.x + threadIdx.x;
    float4 v = ((const float4*)H)[i4];
    int c0 = (i4 * 4) & (cols - 1);
    float o[4] = {v.x, v.y, v.z, v.w};
    #pragma unroll
    for (int e = 0; e < 4; ++e) {
        int c = c0 + e;
        float mu  = sum[c]   * (1.0f / 4096.0f);
        float var = sumsq[c] * (1.0f / 4096.0f) - mu * mu;
        float xn = (o[e] - mu) / sqrtf(var + BN_EPS);
        o[e] = fmaxf(g[c] * xn + beta[c], 0.0f);
    }
    ((float4*)H)[i4] = make_float4(o[0], o[1], o[2], o[3]);
}

// ============ latent = H1 @ W2^T + b2, fused normalize + cluster dists ============
__global__ __launch_bounds__(256) void latent_kernel(
    const float* __restrict__ H1, const float* __restrict__ W2,
    const float* __restrict__ b2, const float* __restrict__ centers,
    float* __restrict__ out_latent, float* __restrict__ out_norm,
    float* __restrict__ out_d1, float* __restrict__ out_d2,
    float* __restrict__ sumy)
{
    __shared__ float W2T[64][32];
    __shared__ float cent[320];
    __shared__ float b2s[32];
    __shared__ float Hs[8][64];
    const int t = threadIdx.x;
    {   // stage W2 transposed: W2 is [32][64] row-major
        int c = t >> 3, dd = (t & 7) * 8;
        #pragma unroll
        for (int q = 0; q < 8; ++q) W2T[dd + q][c] = W2[c * 64 + dd + q];
    }
    for (int c = t; c < 320; c += 256) cent[c] = centers[c];
    if (t < 32) b2s[t] = b2[t];
    const int base = blockIdx.x * 8;
    if (t < 128) {
        int rr = t >> 4, off = (t & 15) * 4;
        *(float4*)&Hs[rr][off] = *(const float4*)&H1[(size_t)(base + rr) * 64 + off];
    }
    __syncthreads();

    const int g = t >> 5, lane = t & 31;
    const int row = base + g;
    float acc = b2s[lane];
    #pragma unroll
    for (int d = 0; d < 64; ++d) acc = fmaf(Hs[g][d], W2T[d][lane], acc);
    out_latent[(size_t)row * 32 + lane] = acc;

    float ss = acc * acc;
    #pragma unroll
    for (int off = 16; off; off >>= 1) ss += __shfl_xor(ss, off);
    float denom = fmaxf(sqrtf(ss), 1e-12f);
    out_norm[(size_t)row * 32 + lane] = acc / denom;
    if (lane == 0) sumy[row] = ss;

    float qsum = 0.f, myx1 = 0.f, myqc = 0.f;
    #pragma unroll
    for (int k = 0; k < 10; ++k) {
        float dv = acc - cent[k * 32 + lane];
        float sq = dv * dv;
        #pragma unroll
        for (int off = 16; off; off >>= 1) sq += __shfl_xor(sq, off);
        float x1 = 1.0f + sq;
        float qc = 1.0f / x1;
        qsum += qc;
        if (lane == k) { myx1 = x1; myqc = qc; }
    }
    if (lane < 10) {
        out_d2[row * 10 + lane] = myx1;
        out_d1[row * 10 + lane] = myqc / qsum;
    }
}

// ============ num kernel v3: 128x128 tile, row-major LDS (pad 33), reg-lean ====
// Thread (tx=t&31, ty=t>>5): rows ty*16+m (m<16), cols tx*4+q (q<4).
// acc[16][4] = 64 VGPR (v2's transposed design spilled: VGPR=256, 680MB scratch
// traffic, 274us). Wave stores = 2 rows x 512B = full 128B lines (fixes v1's
// 64B-segment stores). Pad 33: Lj col-reads 4-way aliased (~1.58x, near-free),
// staging scalar ds_writes 2-way (free).
__global__ __launch_bounds__(256) void num_kernel(
    const float* __restrict__ latent, const float* __restrict__ sumy,
    float* __restrict__ num_out, float* __restrict__ rowsum, float* __restrict__ diagv)
{
    __shared__ float Li[128][33];
    __shared__ float Lj[128][33];
    __shared__ float scr[128];
    const int t  = threadIdx.x;
    const int i0 = blockIdx.x * 128;
    const int j0 = blockIdx.y * 128;
    {   // stage one row per thread: t<128 -> Li row t, t>=128 -> Lj row t-128
        const int r = t & 127;
        const float* src = (t < 128) ? &latent[(size_t)(i0 + r) * 32]
                                     : &latent[(size_t)(j0 + r) * 32];
        float* dst = (t < 128) ? &Li[r][0] : &Lj[r][0];
        float4 v0 = *(const float4*)(src),      v1 = *(const float4*)(src + 4);
        float4 v2 = *(const float4*)(src + 8),  v3 = *(const float4*)(src + 12);
        float4 v4 = *(const float4*)(src + 16), v5 = *(const float4*)(src + 20);
        float4 v6 = *(const float4*)(src + 24), v7 = *(const float4*)(src + 28);
        dst[ 0]=v0.x; dst[ 1]=v0.y; dst[ 2]=v0.z; dst[ 3]=v0.w;
        dst[ 4]=v1.x; dst[ 5]=v1.y; dst[ 6]=v1.z; dst[ 7]=v1.w;
        dst[ 8]=v2.x; dst[ 9]=v2.y; dst[10]=v2.z; dst[11]=v2.w;
        dst[12]=v3.x; dst[13]=v3.y; dst[14]=v3.z; dst[15]=v3.w;
        dst[16]=v4.x; dst[17]=v4.y; dst[18]=v4.z; dst[19]=v4.w;
        dst[20]=v5.x; dst[21]=v5.y; dst[22]=v5.z; dst[23]=v5.w;
        dst[24]=v6.x; dst[25]=v6.y; dst[26]=v6.z; dst[27]=v6.w;
        dst[28]=v7.x; dst[29]=v7.y; dst[30]=v7.z; dst[31]=v7.w;
    }
    if (t < 128) scr[t] = 0.f;
    __syncthreads();

    const int tx = t & 31, ty = t >> 5;   // rows: ty*16+m, cols: tx*4+q
    float acc[16][4] = {};
    #pragma unroll
    for (int d4 = 0; d4 < 8; ++d4) {
        float b0[4], b1[4], b2_[4], b3[4];
        {
            const int c = tx * 4;
            *(float4*)b0  = *(const float4*)&Lj[c+0][d4*4];
            *(float4*)b1  = *(const float4*)&Lj[c+1][d4*4];
            *(float4*)b2_ = *(const float4*)&Lj[c+2][d4*4];
            *(float4*)b3  = *(const float4*)&Lj[c+3][d4*4];
        }
        #pragma unroll
        for (int m = 0; m < 16; ++m) {
            float a[4];
            *(float4*)a = *(const float4*)&Li[ty*16 + m][d4*4];
            #pragma unroll
            for (int e = 0; e < 4; ++e) {
                acc[m][0] = fmaf(a[e], b0[e],  acc[m][0]);
                acc[m][1] = fmaf(a[e], b1[e],  acc[m][1]);
                acc[m][2] = fmaf(a[e], b2_[e], acc[m][2]);
                acc[m][3] = fmaf(a[e], b3[e],  acc[m][3]);
            }
        }
    }
    float4 sj4 = *(const float4*)&sumy[j0 + tx*4];
    float syj[4] = {sj4.x, sj4.y, sj4.z, sj4.w};
    #pragma unroll
    for (int m = 0; m < 16; ++m) {
        const int i = i0 + ty*16 + m;
        const float syi = sumy[i];
        float vq[4], r = 0.f;
        #pragma unroll
        for (int q = 0; q < 4; ++q) {
            const int j = j0 + tx*4 + q;
            float sq = syi + syj[q] - 2.0f * acc[m][q];
            float v = 1.0f / (1.0f + sq);
            vq[q] = v;
            r += v;
            if (i == j) diagv[i] = v;
        }
        *(float4*)&num_out[(size_t)i * NR + j0 + tx*4] =
            make_float4(vq[0], vq[1], vq[2], vq[3]);
        atomicAdd(&scr[ty*16 + m], r);
    }
    __syncthreads();
    if (t < 128) atomicAdd(&rowsum[i0 + t], scr[t]);
}

// ============ fused p+q kernel: one block per row, p kept in registers ============
__global__ __launch_bounds__(256) void pq_kernel(
    const float* __restrict__ num, const float* __restrict__ rowsum,
    const float* __restrict__ diagv, float* __restrict__ p_out,
    float* __restrict__ q_out)
{
    const int i = blockIdx.x;
    const int t = threadIdx.x;
    const float dg = diagv[i];
    const float inv_S1 = 1.0f / (rowsum[i] - dg);
    const float* nrow = &num[(size_t)i * NR];
    float* prow = &p_out[(size_t)i * NR];
    float* qrow = &q_out[(size_t)i * NR];

    float pr[16];
    float s = 0.f, s2 = 0.f;
    #pragma unroll
    for (int it = 0; it < 4; ++it) {
        int j4 = it * 256 + t;
        float4 v = ((const float4*)nrow)[j4];
        float vv[4] = {v.x, v.y, v.z, v.w};
        #pragma unroll
        for (int e = 0; e < 4; ++e) {
            int j = j4 * 4 + e;
            float p = (j == i) ? 0.0f : vv[e] * inv_S1;
            pr[it * 4 + e] = p;
            s += p; s2 += p * p;
        }
        ((float4*)prow)[j4] = make_float4(
            (j4*4+0 == i) ? dg : pr[it*4+0], (j4*4+1 == i) ? dg : pr[it*4+1],
            (j4*4+2 == i) ? dg : pr[it*4+2], (j4*4+3 == i) ? dg : pr[it*4+3]);
    }
    #pragma unroll
    for (int off = 32; off; off >>= 1) {
        s  += __shfl_xor(s, off);
        s2 += __shfl_xor(s2, off);
    }
    __shared__ float rA[4], rB[4];
    const int wid = t >> 6;
    if ((t & 63) == 0) { rA[wid] = s; rB[wid] = s2; }
    __syncthreads();
    const float sp  = rA[0] + rA[1] + rA[2] + rA[3];
    const float sp2 = rB[0] + rB[1] + rB[2] + rB[3];
    const float inv_sp   = 1.0f / sp;
    const float inv_sumq = sp / sp2;     // 1 / (sp2/sp)
    #pragma unroll
    for (int it = 0; it < 4; ++it) {
        int j4 = it * 256 + t;
        float qv[4];
        #pragma unroll
        for (int e = 0; e < 4; ++e) {
            int j = j4 * 4 + e;
            float p = pr[it * 4 + e];
            qv[e] = (j == i) ? dg : (p * p * inv_sp) * inv_sumq;
        }
        ((float4*)qrow)[j4] = make_float4(qv[0], qv[1], qv[2], qv[3]);
    }
}

// ===================== launch =====================
extern "C" void kernel_launch(void* const* d_in, const int* in_sizes, int n_in,
                              void* d_out, int out_size, void* d_ws, size_t ws_size,
                              hipStream_t stream) {
    const float* x       = (const float*)d_in[0];
    const float* W0      = (const float*)d_in[1];
    const float* b0      = (const float*)d_in[2];
    const float* g0      = (const float*)d_in[3];
    const float* beta0   = (const float*)d_in[4];
    const float* W1      = (const float*)d_in[5];
    const float* b1      = (const float*)d_in[6];
    const float* g1      = (const float*)d_in[7];
    const float* beta1   = (const float*)d_in[8];
    const float* W2      = (const float*)d_in[9];
    const float* b2      = (const float*)d_in[10];
    const float* centers = (const float*)d_in[11];
    float* out = (float*)d_out;
    float* ws  = (float*)d_ws;

    // Scratch lives in d_out's latent_q region (dead until pq_kernel).
    float* scr = out + OFF_Q;
    float* H0 = scr + SCR_H0;
    float* H1 = scr + SCR_H1;
    float* P0 = scr + SCR_P0;
    float* P1 = scr + SCR_P1;

    zero_ws<<<19, 256, 0, stream>>>(ws);     // sum0/sq0/sum1/sq1/rowsum

    // ---- layer 0: H0 = x @ W0^T + b0, BN, ReLU (split-K z=10, non-atomic) ----
    gemm_partial_128x64<<<dim3(32, 4, 10), 256, 0, stream>>>(
        x, W0, P0, 2000, 2000, 256, 192, 5, 1048576);
    reduce_bias<<<1024, 256, 0, stream>>>(P0, b0, H0, 10, 262144, 64);
    bn_stats<<<256, 256, 0, stream>>>(H0, ws + WS_SUM0, ws + WS_SQ0, 256);
    bn_relu<<<1024, 256, 0, stream>>>(H0, ws + WS_SUM0, ws + WS_SQ0, g0, beta0, 256);

    // ---- layer 1: H1 = H0 @ W1^T + b1, BN, ReLU (split-K z=4, non-atomic) ----
    gemm_partial_128x64<<<dim3(32, 1, 4), 256, 0, stream>>>(
        H0, W1, P1, 256, 256, 64, 64, 0, 262144);
    reduce_bias<<<256, 256, 0, stream>>>(P1, b1, H1, 4, 65536, 16);
    bn_stats<<<256, 256, 0, stream>>>(H1, ws + WS_SUM1, ws + WS_SQ1, 64);
    bn_relu<<<256, 256, 0, stream>>>(H1, ws + WS_SUM1, ws + WS_SQ1, g1, beta1, 64);

    latent_kernel<<<512, 256, 0, stream>>>(H1, W2, b2, centers,
        out + OFF_LATENT, out + OFF_NORM, out + OFF_D1, out + OFF_D2, ws + WS_SUMY);

    num_kernel<<<dim3(32, 32), 256, 0, stream>>>(out + OFF_LATENT, ws + WS_SUMY,
        out + OFF_NUM, ws + WS_ROWSUM, ws + WS_DIAG);

    pq_kernel<<<4096, 256, 0, stream>>>(out + OFF_NUM, ws + WS_ROWSUM, ws + WS_DIAG,
        out + OFF_P, out + OFF_Q);
}

// Round 11
// 411.452 us; speedup vs baseline: 1.4998x; 1.3353x over previous
//
#include <hip/hip_runtime.h>

#define NR 4096
#define BN_EPS 1e-5f

// ---- d_out offsets (floats), concatenated in reference return order ----
#define OFF_LATENT 0
#define OFF_D1     131072
#define OFF_D2     172032
#define OFF_Q      212992
#define OFF_P      16990208
#define OFF_NUM    33767424
#define OFF_NORM   50544640

// ---- workspace offsets (floats) — small accumulators only (~85 KB) ----
#define WS_SUM0   0
#define WS_SQ0    256
#define WS_SUM1   512
#define WS_SQ1    576
#define WS_ROWSUM 640
#define WS_ZERO_F 4736          // floats to zero (atomic accumulators)
#define WS_DIAG   4736
#define WS_SUMY   8832

// ---- scratch inside d_out's latent_q region (16.77M floats, written last) ----
#define SCR_H0 0
#define SCR_H1 1048576
#define SCR_P0 1310720
#define SCR_P1 11796480

// ============ zero the atomic accumulators (graph-capture-safe) ============
__global__ void zero_ws(float* __restrict__ ws) {
    int i = blockIdx.x * blockDim.x + threadIdx.x;
    if (i < WS_ZERO_F) ws[i] = 0.0f;
}

// ============ split-K GEMM, NON-ATOMIC partials: P[z] = A_chunk @ B_chunk^T ====
// 128x64 tile, 8x4 micro-tile, BK=16, 256 threads, register-staged prefetch.
__global__ __launch_bounds__(256) void gemm_partial_128x64(
    const float* __restrict__ A, const float* __restrict__ B,
    float* __restrict__ P, int lda, int ldb, int ldn,
    int kcB, int extra, int pstride)
{
    __shared__ float As[16][128];   // transposed: As[k][row]
    __shared__ float Bs[16][64];
    const int t  = threadIdx.x;
    const int tx = t & 15;          // col group (4 cols)
    const int ty = t >> 4;          // row group (8 rows)
    const int i0 = blockIdx.x * 128;
    const int n0 = blockIdx.y * 64;
    const int z  = blockIdx.z;
    const int kc = kcB + (z < extra ? 16 : 0);
    const int kb = z * kcB + (z < extra ? z : extra) * 16;

    const int ra  = t >> 1;         // 0..127 (A row)
    const int ka  = (t & 1) * 8;    // 0 or 8
    const int rb  = t >> 2;         // 0..63  (B row)
    const int kbq = (t & 3) * 4;    // 0,4,8,12

    const float* pA = &A[(size_t)(i0 + ra) * lda + kb + ka];
    const float* pB = &B[(size_t)(n0 + rb) * ldb + kb + kbq];

    float acc[8][4] = {};

    float4 a0 = *(const float4*)(pA);
    float4 a1 = *(const float4*)(pA + 4);
    float4 b0 = *(const float4*)(pB);

    for (int kt = 0; kt < kc; kt += 16) {
        __syncthreads();
        As[ka+0][ra] = a0.x; As[ka+1][ra] = a0.y; As[ka+2][ra] = a0.z; As[ka+3][ra] = a0.w;
        As[ka+4][ra] = a1.x; As[ka+5][ra] = a1.y; As[ka+6][ra] = a1.z; As[ka+7][ra] = a1.w;
        Bs[kbq+0][rb] = b0.x; Bs[kbq+1][rb] = b0.y; Bs[kbq+2][rb] = b0.z; Bs[kbq+3][rb] = b0.w;
        __syncthreads();
        if (kt + 16 < kc) {         // next-tile loads in flight during compute
            a0 = *(const float4*)(pA + kt + 16);
            a1 = *(const float4*)(pA + kt + 20);
            b0 = *(const float4*)(pB + kt + 16);
        }
        #pragma unroll
        for (int k = 0; k < 16; ++k) {
            float4 av0 = *(const float4*)&As[k][ty*8];
            float4 av1 = *(const float4*)&As[k][ty*8+4];
            float4 bv  = *(const float4*)&Bs[k][tx*4];
            float am[8] = {av0.x,av0.y,av0.z,av0.w,av1.x,av1.y,av1.z,av1.w};
            float bb[4] = {bv.x,bv.y,bv.z,bv.w};
            #pragma unroll
            for (int m = 0; m < 8; ++m)
                #pragma unroll
                for (int n = 0; n < 4; ++n)
                    acc[m][n] = fmaf(am[m], bb[n], acc[m][n]);
        }
    }
    float* dst = P + (size_t)z * pstride;
    #pragma unroll
    for (int m = 0; m < 8; ++m)
        *(float4*)&dst[(size_t)(i0 + ty*8 + m) * ldn + n0 + tx*4] =
            make_float4(acc[m][0], acc[m][1], acc[m][2], acc[m][3]);
}

// ============ H = bias + sum_z P[z]  (deterministic K-reduction) ============
__global__ void reduce_bias(const float* __restrict__ P, const float* __restrict__ bias,
                            float* __restrict__ H, int nz, int pstride4, int cols4)
{
    int i4 = blockIdx.x * blockDim.x + threadIdx.x;
    float4 a = ((const float4*)bias)[i4 & (cols4 - 1)];
    for (int z = 0; z < nz; ++z) {
        float4 v = ((const float4*)P)[(size_t)z * pstride4 + i4];
        a.x += v.x; a.y += v.y; a.z += v.z; a.w += v.w;
    }
    ((float4*)H)[i4] = a;
}

// ============ BatchNorm column stats: sum / sumsq via atomics ============
__global__ void bn_stats(const float* __restrict__ H, float* __restrict__ sum,
                         float* __restrict__ sumsq, int cols)
{
    const int t = threadIdx.x;
    const int col = t & (cols - 1);
    const int sub = t / cols;
    const int rstep = 256 / cols;
    const int rbase = blockIdx.x * 16;
    float s = 0.f, sq = 0.f;
    for (int r = sub; r < 16; r += rstep) {
        float v = H[(size_t)(rbase + r) * cols + col];
        s += v; sq += v * v;
    }
    atomicAdd(&sum[col], s);
    atomicAdd(&sumsq[col], sq);
}

// ============ BN apply + ReLU (in place, float4) ============
__global__ void bn_relu(float* __restrict__ H, const float* __restrict__ sum,
                        const float* __restrict__ sumsq, const float* __restrict__ g,
                        const float* __restrict__ beta, int cols)
{
    int i4 = blockIdx.x * blockDim.x + threadIdx.x;
    float4 v = ((const float4*)H)[i4];
    int c0 = (i4 * 4) & (cols - 1);
    float o[4] = {v.x, v.y, v.z, v.w};
    #pragma unroll
    for (int e = 0; e < 4; ++e) {
        int c = c0 + e;
        float mu  = sum[c]   * (1.0f / 4096.0f);
        float var = sumsq[c] * (1.0f / 4096.0f) - mu * mu;
        float xn = (o[e] - mu) / sqrtf(var + BN_EPS);
        o[e] = fmaxf(g[c] * xn + beta[c], 0.0f);
    }
    ((float4*)H)[i4] = make_float4(o[0], o[1], o[2], o[3]);
}

// ============ latent = H1 @ W2^T + b2, fused normalize + cluster dists ============
__global__ __launch_bounds__(256) void latent_kernel(
    const float* __restrict__ H1, const float* __restrict__ W2,
    const float* __restrict__ b2, const float* __restrict__ centers,
    float* __restrict__ out_latent, float* __restrict__ out_norm,
    float* __restrict__ out_d1, float* __restrict__ out_d2,
    float* __restrict__ sumy)
{
    __shared__ float W2T[64][32];
    __shared__ float cent[320];
    __shared__ float b2s[32];
    __shared__ float Hs[8][64];
    const int t = threadIdx.x;
    {   // stage W2 transposed: W2 is [32][64] row-major
        int c = t >> 3, dd = (t & 7) * 8;
        #pragma unroll
        for (int q = 0; q < 8; ++q) W2T[dd + q][c] = W2[c * 64 + dd + q];
    }
    for (int c = t; c < 320; c += 256) cent[c] = centers[c];
    if (t < 32) b2s[t] = b2[t];
    const int base = blockIdx.x * 8;
    if (t < 128) {
        int rr = t >> 4, off = (t & 15) * 4;
        *(float4*)&Hs[rr][off] = *(const float4*)&H1[(size_t)(base + rr) * 64 + off];
    }
    __syncthreads();

    const int g = t >> 5, lane = t & 31;
    const int row = base + g;
    float acc = b2s[lane];
    #pragma unroll
    for (int d = 0; d < 64; ++d) acc = fmaf(Hs[g][d], W2T[d][lane], acc);
    out_latent[(size_t)row * 32 + lane] = acc;

    float ss = acc * acc;
    #pragma unroll
    for (int off = 16; off; off >>= 1) ss += __shfl_xor(ss, off);
    float denom = fmaxf(sqrtf(ss), 1e-12f);
    out_norm[(size_t)row * 32 + lane] = acc / denom;
    if (lane == 0) sumy[row] = ss;

    float qsum = 0.f, myx1 = 0.f, myqc = 0.f;
    #pragma unroll
    for (int k = 0; k < 10; ++k) {
        float dv = acc - cent[k * 32 + lane];
        float sq = dv * dv;
        #pragma unroll
        for (int off = 16; off; off >>= 1) sq += __shfl_xor(sq, off);
        float x1 = 1.0f + sq;
        float qc = 1.0f / x1;
        qsum += qc;
        if (lane == k) { myx1 = x1; myqc = qc; }
    }
    if (lane < 10) {
        out_d2[row * 10 + lane] = myx1;
        out_d1[row * 10 + lane] = myqc / qsum;
    }
}

// ============ num kernel v4: 128x64 tile; A in LDS, B direct-from-global ======
// v2/v3 lesson (counter-verified): fully-unrolled d-loops let the scheduler
// hoist ALL B-loads -> VGPR=256 + spills (680/570MB scratch traffic). v4:
// acc[8][4]=32 regs, d4 loop is "#pragma unroll 1" so at most one iteration's
// 16 B-floats are in flight — registers structurally bounded (~100). B comes
// straight from global (latent = 512KB, L2/L3-resident; 8KB/block). A-reads
// from LDS are 16-lane broadcasts (conflict-free, pad 36 keeps 16B alignment).
// Stores: wave = 4 rows x 256B contiguous float4 — fully coalesced.
__global__ __launch_bounds__(256) void num_kernel(
    const float* __restrict__ latent, const float* __restrict__ sumy,
    float* __restrict__ num_out, float* __restrict__ rowsum, float* __restrict__ diagv)
{
    __shared__ float Li[128][36];
    __shared__ float scr[128];
    const int t  = threadIdx.x;
    const int i0 = blockIdx.x * 128;
    const int j0 = blockIdx.y * 64;
    {   // stage A rows: 2 threads/row, 16 floats each, aligned float4 LDS writes
        const int r = t >> 1, h = (t & 1) * 16;
        const float* src = &latent[(size_t)(i0 + r) * 32 + h];
        float* dst = &Li[r][h];
        *(float4*)(dst + 0)  = *(const float4*)(src + 0);
        *(float4*)(dst + 4)  = *(const float4*)(src + 4);
        *(float4*)(dst + 8)  = *(const float4*)(src + 8);
        *(float4*)(dst + 12) = *(const float4*)(src + 12);
    }
    if (t < 128) scr[t] = 0.f;
    __syncthreads();

    const int tx = t & 15, ty = t >> 4;   // rows: ty+16m (m<8), cols: tx*4+q
    const float* bptr = &latent[(size_t)(j0 + tx * 4) * 32];

    float acc[8][4] = {};
    #pragma unroll 1
    for (int d4 = 0; d4 < 8; ++d4) {
        float b[4][4];
        *(float4*)b[0] = *(const float4*)(bptr + 0 * 32 + d4 * 4);
        *(float4*)b[1] = *(const float4*)(bptr + 1 * 32 + d4 * 4);
        *(float4*)b[2] = *(const float4*)(bptr + 2 * 32 + d4 * 4);
        *(float4*)b[3] = *(const float4*)(bptr + 3 * 32 + d4 * 4);
        #pragma unroll
        for (int m = 0; m < 8; ++m) {
            float a[4];
            *(float4*)a = *(const float4*)&Li[ty + 16 * m][d4 * 4];
            #pragma unroll
            for (int e = 0; e < 4; ++e) {
                acc[m][0] = fmaf(a[e], b[0][e], acc[m][0]);
                acc[m][1] = fmaf(a[e], b[1][e], acc[m][1]);
                acc[m][2] = fmaf(a[e], b[2][e], acc[m][2]);
                acc[m][3] = fmaf(a[e], b[3][e], acc[m][3]);
            }
        }
    }
    float4 sj4 = *(const float4*)&sumy[j0 + tx * 4];
    float syj[4] = {sj4.x, sj4.y, sj4.z, sj4.w};
    #pragma unroll
    for (int m = 0; m < 8; ++m) {
        const int i = i0 + ty + 16 * m;
        const float syi = sumy[i];
        float vq[4], r = 0.f;
        #pragma unroll
        for (int q = 0; q < 4; ++q) {
            const int j = j0 + tx * 4 + q;
            float sq = syi + syj[q] - 2.0f * acc[m][q];
            float v = 1.0f / (1.0f + sq);
            vq[q] = v;
            r += v;
            if (i == j) diagv[i] = v;
        }
        *(float4*)&num_out[(size_t)i * NR + j0 + tx * 4] =
            make_float4(vq[0], vq[1], vq[2], vq[3]);
        atomicAdd(&scr[ty + 16 * m], r);
    }
    __syncthreads();
    if (t < 128) atomicAdd(&rowsum[i0 + t], scr[t]);
}

// ============ fused p+q kernel: one block per row, p kept in registers ============
__global__ __launch_bounds__(256) void pq_kernel(
    const float* __restrict__ num, const float* __restrict__ rowsum,
    const float* __restrict__ diagv, float* __restrict__ p_out,
    float* __restrict__ q_out)
{
    const int i = blockIdx.x;
    const int t = threadIdx.x;
    const float dg = diagv[i];
    const float inv_S1 = 1.0f / (rowsum[i] - dg);
    const float* nrow = &num[(size_t)i * NR];
    float* prow = &p_out[(size_t)i * NR];
    float* qrow = &q_out[(size_t)i * NR];

    float pr[16];
    float s = 0.f, s2 = 0.f;
    #pragma unroll
    for (int it = 0; it < 4; ++it) {
        int j4 = it * 256 + t;
        float4 v = ((const float4*)nrow)[j4];
        float vv[4] = {v.x, v.y, v.z, v.w};
        #pragma unroll
        for (int e = 0; e < 4; ++e) {
            int j = j4 * 4 + e;
            float p = (j == i) ? 0.0f : vv[e] * inv_S1;
            pr[it * 4 + e] = p;
            s += p; s2 += p * p;
        }
        ((float4*)prow)[j4] = make_float4(
            (j4*4+0 == i) ? dg : pr[it*4+0], (j4*4+1 == i) ? dg : pr[it*4+1],
            (j4*4+2 == i) ? dg : pr[it*4+2], (j4*4+3 == i) ? dg : pr[it*4+3]);
    }
    #pragma unroll
    for (int off = 32; off; off >>= 1) {
        s  += __shfl_xor(s, off);
        s2 += __shfl_xor(s2, off);
    }
    __shared__ float rA[4], rB[4];
    const int wid = t >> 6;
    if ((t & 63) == 0) { rA[wid] = s; rB[wid] = s2; }
    __syncthreads();
    const float sp  = rA[0] + rA[1] + rA[2] + rA[3];
    const float sp2 = rB[0] + rB[1] + rB[2] + rB[3];
    const float inv_sp   = 1.0f / sp;
    const float inv_sumq = sp / sp2;     // 1 / (sp2/sp)
    #pragma unroll
    for (int it = 0; it < 4; ++it) {
        int j4 = it * 256 + t;
        float qv[4];
        #pragma unroll
        for (int e = 0; e < 4; ++e) {
            int j = j4 * 4 + e;
            float p = pr[it * 4 + e];
            qv[e] = (j == i) ? dg : (p * p * inv_sp) * inv_sumq;
        }
        ((float4*)qrow)[j4] = make_float4(qv[0], qv[1], qv[2], qv[3]);
    }
}

// ===================== launch =====================
extern "C" void kernel_launch(void* const* d_in, const int* in_sizes, int n_in,
                              void* d_out, int out_size, void* d_ws, size_t ws_size,
                              hipStream_t stream) {
    const float* x       = (const float*)d_in[0];
    const float* W0      = (const float*)d_in[1];
    const float* b0      = (const float*)d_in[2];
    const float* g0      = (const float*)d_in[3];
    const float* beta0   = (const float*)d_in[4];
    const float* W1      = (const float*)d_in[5];
    const float* b1      = (const float*)d_in[6];
    const float* g1      = (const float*)d_in[7];
    const float* beta1   = (const float*)d_in[8];
    const float* W2      = (const float*)d_in[9];
    const float* b2      = (const float*)d_in[10];
    const float* centers = (const float*)d_in[11];
    float* out = (float*)d_out;
    float* ws  = (float*)d_ws;

    // Scratch lives in d_out's latent_q region (dead until pq_kernel).
    float* scr = out + OFF_Q;
    float* H0 = scr + SCR_H0;
    float* H1 = scr + SCR_H1;
    float* P0 = scr + SCR_P0;
    float* P1 = scr + SCR_P1;

    zero_ws<<<19, 256, 0, stream>>>(ws);     // sum0/sq0/sum1/sq1/rowsum

    // ---- layer 0: H0 = x @ W0^T + b0, BN, ReLU (split-K z=10, non-atomic) ----
    gemm_partial_128x64<<<dim3(32, 4, 10), 256, 0, stream>>>(
        x, W0, P0, 2000, 2000, 256, 192, 5, 1048576);
    reduce_bias<<<1024, 256, 0, stream>>>(P0, b0, H0, 10, 262144, 64);
    bn_stats<<<256, 256, 0, stream>>>(H0, ws + WS_SUM0, ws + WS_SQ0, 256);
    bn_relu<<<1024, 256, 0, stream>>>(H0, ws + WS_SUM0, ws + WS_SQ0, g0, beta0, 256);

    // ---- layer 1: H1 = H0 @ W1^T + b1, BN, ReLU (split-K z=4, non-atomic) ----
    gemm_partial_128x64<<<dim3(32, 1, 4), 256, 0, stream>>>(
        H0, W1, P1, 256, 256, 64, 64, 0, 262144);
    reduce_bias<<<256, 256, 0, stream>>>(P1, b1, H1, 4, 65536, 16);
    bn_stats<<<256, 256, 0, stream>>>(H1, ws + WS_SUM1, ws + WS_SQ1, 64);
    bn_relu<<<256, 256, 0, stream>>>(H1, ws + WS_SUM1, ws + WS_SQ1, g1, beta1, 64);

    latent_kernel<<<512, 256, 0, stream>>>(H1, W2, b2, centers,
        out + OFF_LATENT, out + OFF_NORM, out + OFF_D1, out + OFF_D2, ws + WS_SUMY);

    num_kernel<<<dim3(32, 64), 256, 0, stream>>>(out + OFF_LATENT, ws + WS_SUMY,
        out + OFF_NUM, ws + WS_ROWSUM, ws + WS_DIAG);

    pq_kernel<<<4096, 256, 0, stream>>>(out + OFF_NUM, ws + WS_ROWSUM, ws + WS_DIAG,
        out + OFF_P, out + OFF_Q);
}